// Round 1
// baseline (1174.157 us; speedup 1.0000x reference)
//
#include <hip/hip_runtime.h>
#include <math.h>

#define SEQ   2048
#define HID   1024
#define INTER 2048
#define DST   16
#define DTR   64
#define NP    96   // DTR + 2*DST

__device__ __forceinline__ float sigmoidf_(float x) { return 1.0f / (1.0f + expf(-x)); }
__device__ __forceinline__ float siluf_(float x)    { return x * sigmoidf_(x); }
__device__ __forceinline__ float softplusf_(float x){ return (x > 20.0f) ? x : log1pf(expf(x)); }

// ---------------------------------------------------------------------------
// Generic tiled fp32 GEMM: C[M,N] = A[M,K] @ B[K,N], row-major, 256 threads.
// ---------------------------------------------------------------------------
template<int BM, int BN, int BK, int TM, int TN>
__global__ __launch_bounds__(256) void gemm_f32(const float* __restrict__ A,
                                                const float* __restrict__ B,
                                                float* __restrict__ C,
                                                int M, int N, int K)
{
    __shared__ float Ast[BK][BM];   // A tile, transposed
    __shared__ float Bs[BK][BN];

    const int tid = threadIdx.x;
    constexpr int NTX = BN / TN;
    const int tx = tid % NTX;
    const int ty = tid / NTX;
    const int m0 = blockIdx.y * BM;
    const int n0 = blockIdx.x * BN;

    float acc[TM][TN];
#pragma unroll
    for (int i = 0; i < TM; ++i)
#pragma unroll
        for (int j = 0; j < TN; ++j) acc[i][j] = 0.0f;

    constexpr int AV = (BM * BK) / (256 * 4);   // float4 loads of A per thread
    constexpr int BV = (BK * BN) / (256 * 4);

    for (int k0 = 0; k0 < K; k0 += BK) {
#pragma unroll
        for (int t = 0; t < AV; ++t) {
            int v = tid + t * 256;
            int row = v / (BK / 4);
            int seg = v % (BK / 4);
            float4 x = *(const float4*)&A[(size_t)(m0 + row) * K + k0 + seg * 4];
            Ast[seg * 4 + 0][row] = x.x;
            Ast[seg * 4 + 1][row] = x.y;
            Ast[seg * 4 + 2][row] = x.z;
            Ast[seg * 4 + 3][row] = x.w;
        }
#pragma unroll
        for (int t = 0; t < BV; ++t) {
            int v = tid + t * 256;
            int row = v / (BN / 4);
            int col = v % (BN / 4);
            *(float4*)&Bs[row][col * 4] =
                *(const float4*)&B[(size_t)(k0 + row) * N + n0 + col * 4];
        }
        __syncthreads();

#pragma unroll
        for (int k = 0; k < BK; ++k) {
            float a[TM], b[TN];
#pragma unroll
            for (int i = 0; i < TM / 4; ++i)
                *(float4*)&a[i * 4] = *(const float4*)&Ast[k][ty * TM + i * 4];
#pragma unroll
            for (int j = 0; j < TN / 4; ++j)
                *(float4*)&b[j * 4] = *(const float4*)&Bs[k][tx * TN + j * 4];
#pragma unroll
            for (int i = 0; i < TM; ++i)
#pragma unroll
                for (int j = 0; j < TN; ++j)
                    acc[i][j] = fmaf(a[i], b[j], acc[i][j]);
        }
        __syncthreads();
    }

#pragma unroll
    for (int i = 0; i < TM; ++i)
#pragma unroll
        for (int j = 0; j < TN / 4; ++j) {
            float4 o;
            o.x = acc[i][j * 4 + 0];
            o.y = acc[i][j * 4 + 1];
            o.z = acc[i][j * 4 + 2];
            o.w = acc[i][j * 4 + 3];
            *(float4*)&C[(size_t)(m0 + ty * TM + i) * N + n0 + tx * TN + j * 4] = o;
        }
}

// ---------------------------------------------------------------------------
// Depthwise causal conv (K=4) + bias + SiLU.  raw = proj[:, :INTER]
// ---------------------------------------------------------------------------
__global__ __launch_bounds__(256) void conv_silu(const float* __restrict__ proj,
                                                 const float* __restrict__ cw,
                                                 const float* __restrict__ cb,
                                                 float* __restrict__ hbuf)
{
    int idx = blockIdx.x * 256 + threadIdx.x;   // over SEQ*INTER, c fastest
    int c = idx % INTER;
    int s = idx / INTER;
    float acc = cb[c];
#pragma unroll
    for (int k = 0; k < 4; ++k) {
        int sp = s + k - 3;
        if (sp >= 0)
            acc = fmaf(proj[(size_t)sp * (2 * INTER) + c], cw[k * INTER + c], acc);
    }
    hbuf[idx] = siluf_(acc);
}

// ---------------------------------------------------------------------------
// h @ W_x  (K split into 8 chunks of 256) -> partials[chunk][SEQ][96]
// ---------------------------------------------------------------------------
__global__ __launch_bounds__(256) void gemm_hwx(const float* __restrict__ hbuf,
                                                const float* __restrict__ Wx,
                                                float* __restrict__ partials)
{
    __shared__ float hst[16][64];   // transposed h tile
    __shared__ float wxs[16][96];

    const int tid = threadIdx.x;
    const int tx = tid % 16;        // 16 col groups of 6
    const int ty = tid / 16;        // 16 row groups of 4
    const int m0 = blockIdx.x * 64;
    const int kc0 = blockIdx.y * 256;

    float acc[4][6];
#pragma unroll
    for (int i = 0; i < 4; ++i)
#pragma unroll
        for (int j = 0; j < 6; ++j) acc[i][j] = 0.0f;

    for (int kt = 0; kt < 16; ++kt) {
        const int k0 = kc0 + kt * 16;
        {
            int row = tid >> 2, seg = tid & 3;
            float4 v = *(const float4*)&hbuf[(size_t)(m0 + row) * INTER + k0 + seg * 4];
            hst[seg * 4 + 0][row] = v.x;
            hst[seg * 4 + 1][row] = v.y;
            hst[seg * 4 + 2][row] = v.z;
            hst[seg * 4 + 3][row] = v.w;
        }
        for (int j = tid; j < 16 * 96; j += 256)
            wxs[j / 96][j % 96] = Wx[(size_t)(k0 + j / 96) * NP + (j % 96)];
        __syncthreads();

#pragma unroll
        for (int k = 0; k < 16; ++k) {
            float a[4], b[6];
#pragma unroll
            for (int i = 0; i < 4; ++i) a[i] = hst[k][ty * 4 + i];
#pragma unroll
            for (int j = 0; j < 6; ++j) b[j] = wxs[k][tx * 6 + j];
#pragma unroll
            for (int i = 0; i < 4; ++i)
#pragma unroll
                for (int j = 0; j < 6; ++j)
                    acc[i][j] = fmaf(a[i], b[j], acc[i][j]);
        }
        __syncthreads();
    }

    float* P = partials + (size_t)blockIdx.y * (SEQ * NP);
#pragma unroll
    for (int i = 0; i < 4; ++i)
#pragma unroll
        for (int j = 0; j < 6; ++j)
            P[(size_t)(m0 + ty * 4 + i) * NP + tx * 6 + j] = acc[i][j];
}

__global__ __launch_bounds__(256) void reduce_partials(const float* __restrict__ partials,
                                                       float* __restrict__ ssm_p)
{
    int i = blockIdx.x * 256 + threadIdx.x;
    if (i < SEQ * NP) {
        float a = 0.0f;
#pragma unroll
        for (int c = 0; c < 8; ++c) a += partials[(size_t)c * (SEQ * NP) + i];
        ssm_p[i] = a;
    }
}

// ---------------------------------------------------------------------------
// dt = softplus(ts @ W_dt + b_dt); ts = ssm_p[:, :64]
// ---------------------------------------------------------------------------
__global__ __launch_bounds__(256) void dt_gemm(const float* __restrict__ ssm_p,
                                               const float* __restrict__ Wdt,
                                               const float* __restrict__ bdt,
                                               float* __restrict__ dtb)
{
    __shared__ float tss[16][64];
    const int tid = threadIdx.x;
    const int s0 = blockIdx.y * 16;
    const int n = blockIdx.x * 256 + tid;

    for (int j = tid; j < 16 * 64; j += 256) {
        int r = j >> 6, k = j & 63;
        tss[r][k] = ssm_p[(size_t)(s0 + r) * NP + k];
    }
    __syncthreads();

    float bv = bdt[n];
    float acc[16];
#pragma unroll
    for (int r = 0; r < 16; ++r) acc[r] = bv;

    for (int k = 0; k < 64; ++k) {
        float w = Wdt[(size_t)k * INTER + n];
#pragma unroll
        for (int r = 0; r < 16; ++r) acc[r] = fmaf(tss[r][k], w, acc[r]);
    }
#pragma unroll
    for (int r = 0; r < 16; ++r)
        dtb[(size_t)(s0 + r) * INTER + n] = softplusf_(acc[r]);
}

// ---------------------------------------------------------------------------
// SSM sequential scan, fused with +h*D and *silu(gate).
// Block: 8 channels x 16 d = 128 threads.  Chunked LDS staging of 64 steps.
// ---------------------------------------------------------------------------
__global__ __launch_bounds__(128) void ssm_scan(const float* __restrict__ dtb,
                                                const float* __restrict__ hbuf,
                                                const float* __restrict__ ssm_p,
                                                const float* __restrict__ proj,
                                                const float* __restrict__ A_log,
                                                const float* __restrict__ Dvec,
                                                float* __restrict__ ybuf)
{
    const int tid = threadIdx.x;
    const int lc = tid >> 4;      // local channel 0..7
    const int d  = tid & 15;
    const int hh0 = blockIdx.x * 8;
    const int hh = hh0 + lc;

    __shared__ float dts[64][8];
    __shared__ float hvs[64][8];
    __shared__ float gbs[64][8];
    __shared__ float ys [64][8];
    __shared__ float Bc [64][16];
    __shared__ float Cc [64][16];

    const float Av = -expf(A_log[(size_t)hh * DST + d]);
    const float Dv = Dvec[hh];
    float state = 0.0f;

    for (int s0 = 0; s0 < SEQ; s0 += 64) {
        for (int j = tid; j < 64 * 8; j += 128) {
            int r = j >> 3, c = j & 7;
            dts[r][c] = dtb[(size_t)(s0 + r) * INTER + hh0 + c];
            hvs[r][c] = hbuf[(size_t)(s0 + r) * INTER + hh0 + c];
            gbs[r][c] = proj[(size_t)(s0 + r) * (2 * INTER) + INTER + hh0 + c];
        }
        for (int j = tid; j < 64 * 16; j += 128) {
            int r = j >> 4, c = j & 15;
            Bc[r][c] = ssm_p[(size_t)(s0 + r) * NP + DTR + c];
            Cc[r][c] = ssm_p[(size_t)(s0 + r) * NP + DTR + DST + c];
        }
        __syncthreads();

        for (int r = 0; r < 64; ++r) {
            float dtv = dts[r][lc];
            float hv  = hvs[r][lc];
            float da  = expf(dtv * Av);
            float dbu = dtv * Bc[r][d] * hv;
            state = fmaf(da, state, dbu);
            float p = state * Cc[r][d];
            p += __shfl_xor(p, 8);
            p += __shfl_xor(p, 4);
            p += __shfl_xor(p, 2);
            p += __shfl_xor(p, 1);
            if (d == 0) {
                float g = gbs[r][lc];
                ys[r][lc] = (p + hv * Dv) * siluf_(g);
            }
        }
        __syncthreads();

        for (int j = tid; j < 64 * 8; j += 128) {
            int r = j >> 3, c = j & 7;
            ybuf[(size_t)(s0 + r) * INTER + hh0 + c] = ys[r][c];
        }
        __syncthreads();
    }
}

// ---------------------------------------------------------------------------
extern "C" void kernel_launch(void* const* d_in, const int* in_sizes, int n_in,
                              void* d_out, int out_size, void* d_ws, size_t ws_size,
                              hipStream_t stream)
{
    const float* x      = (const float*)d_in[0];
    const float* W_in   = (const float*)d_in[1];
    const float* conv_w = (const float*)d_in[2];
    const float* conv_b = (const float*)d_in[3];
    const float* W_x    = (const float*)d_in[4];
    const float* W_dt   = (const float*)d_in[5];
    const float* b_dt   = (const float*)d_in[6];
    const float* A_log  = (const float*)d_in[7];
    const float* Dv     = (const float*)d_in[8];
    const float* W_out  = (const float*)d_in[9];
    float* out = (float*)d_out;

    float* ws    = (float*)d_ws;
    float* proj  = ws;                           // SEQ*4096
    float* hbuf  = proj + (size_t)SEQ * 4096;    // SEQ*INTER
    float* dtb   = hbuf + (size_t)SEQ * INTER;   // SEQ*INTER
    float* ybuf  = dtb  + (size_t)SEQ * INTER;   // SEQ*INTER
    float* ssm_p = ybuf + (size_t)SEQ * INTER;   // SEQ*NP
    float* parts = ssm_p + (size_t)SEQ * NP;     // 8*SEQ*NP

    // 1) proj = x @ W_in   (2048 x 4096 x 1024)
    gemm_f32<128, 128, 16, 8, 8><<<dim3(4096 / 128, SEQ / 128), 256, 0, stream>>>(
        x, W_in, proj, SEQ, 2 * INTER, HID);

    // 2) h = silu(causal depthwise conv(raw) + b)
    conv_silu<<<(SEQ * INTER) / 256, 256, 0, stream>>>(proj, conv_w, conv_b, hbuf);

    // 3) ssm_p = h @ W_x   (split-K=8 + reduce)
    gemm_hwx<<<dim3(SEQ / 64, 8), 256, 0, stream>>>(hbuf, W_x, parts);
    reduce_partials<<<(SEQ * NP + 255) / 256, 256, 0, stream>>>(parts, ssm_p);

    // 4) dt = softplus(ts @ W_dt + b_dt)
    dt_gemm<<<dim3(INTER / 256, SEQ / 16), 256, 0, stream>>>(ssm_p, W_dt, b_dt, dtb);

    // 5) SSM scan fused with +h*D and *silu(gate)
    ssm_scan<<<INTER / 8, 128, 0, stream>>>(dtb, hbuf, ssm_p, proj, A_log, Dv, ybuf);

    // 6) out = y @ W_out   (2048 x 1024 x 2048)
    gemm_f32<64, 128, 16, 4, 8><<<dim3(HID / 128, SEQ / 64), 256, 0, stream>>>(
        ybuf, W_out, out, SEQ, HID, INTER);
}

// Round 2
// 548.730 us; speedup vs baseline: 2.1398x; 2.1398x over previous
//
#include <hip/hip_runtime.h>
#include <math.h>

#define SEQ   2048
#define HID   1024
#define INTER 2048
#define DST   16
#define DTR   64
#define NP    96   // DTR + 2*DST
#define NC    64   // scan chunks
#define LCH   32   // steps per chunk (NC*LCH == SEQ)

__device__ __forceinline__ float sigmoidf_(float x) { return 1.0f / (1.0f + expf(-x)); }
__device__ __forceinline__ float siluf_(float x)    { return x * sigmoidf_(x); }
__device__ __forceinline__ float softplusf_(float x){ return (x > 20.0f) ? x : log1pf(expf(x)); }

// ---------------------------------------------------------------------------
// Generic tiled fp32 GEMM: C[M,N] = A[M,K] @ B[K,N], row-major, 256 threads.
// ---------------------------------------------------------------------------
template<int BM, int BN, int BK, int TM, int TN>
__global__ __launch_bounds__(256) void gemm_f32(const float* __restrict__ A,
                                                const float* __restrict__ B,
                                                float* __restrict__ C,
                                                int M, int N, int K)
{
    __shared__ float Ast[BK][BM];   // A tile, transposed
    __shared__ float Bs[BK][BN];

    const int tid = threadIdx.x;
    constexpr int NTX = BN / TN;
    const int tx = tid % NTX;
    const int ty = tid / NTX;
    const int m0 = blockIdx.y * BM;
    const int n0 = blockIdx.x * BN;

    float acc[TM][TN];
#pragma unroll
    for (int i = 0; i < TM; ++i)
#pragma unroll
        for (int j = 0; j < TN; ++j) acc[i][j] = 0.0f;

    constexpr int AV = (BM * BK) / (256 * 4);   // float4 loads of A per thread
    constexpr int BV = (BK * BN) / (256 * 4);

    for (int k0 = 0; k0 < K; k0 += BK) {
#pragma unroll
        for (int t = 0; t < AV; ++t) {
            int v = tid + t * 256;
            int row = v / (BK / 4);
            int seg = v % (BK / 4);
            float4 x = *(const float4*)&A[(size_t)(m0 + row) * K + k0 + seg * 4];
            Ast[seg * 4 + 0][row] = x.x;
            Ast[seg * 4 + 1][row] = x.y;
            Ast[seg * 4 + 2][row] = x.z;
            Ast[seg * 4 + 3][row] = x.w;
        }
#pragma unroll
        for (int t = 0; t < BV; ++t) {
            int v = tid + t * 256;
            int row = v / (BN / 4);
            int col = v % (BN / 4);
            *(float4*)&Bs[row][col * 4] =
                *(const float4*)&B[(size_t)(k0 + row) * N + n0 + col * 4];
        }
        __syncthreads();

#pragma unroll
        for (int k = 0; k < BK; ++k) {
            float a[TM], b[TN];
#pragma unroll
            for (int i = 0; i < TM / 4; ++i)
                *(float4*)&a[i * 4] = *(const float4*)&Ast[k][ty * TM + i * 4];
#pragma unroll
            for (int j = 0; j < TN / 4; ++j)
                *(float4*)&b[j * 4] = *(const float4*)&Bs[k][tx * TN + j * 4];
#pragma unroll
            for (int i = 0; i < TM; ++i)
#pragma unroll
                for (int j = 0; j < TN; ++j)
                    acc[i][j] = fmaf(a[i], b[j], acc[i][j]);
        }
        __syncthreads();
    }

#pragma unroll
    for (int i = 0; i < TM; ++i)
#pragma unroll
        for (int j = 0; j < TN / 4; ++j) {
            float4 o;
            o.x = acc[i][j * 4 + 0];
            o.y = acc[i][j * 4 + 1];
            o.z = acc[i][j * 4 + 2];
            o.w = acc[i][j * 4 + 3];
            *(float4*)&C[(size_t)(m0 + ty * TM + i) * N + n0 + tx * TN + j * 4] = o;
        }
}

// ---------------------------------------------------------------------------
// Depthwise causal conv (K=4) + bias + SiLU.  raw = proj[:, :INTER]
// ---------------------------------------------------------------------------
__global__ __launch_bounds__(256) void conv_silu(const float* __restrict__ proj,
                                                 const float* __restrict__ cw,
                                                 const float* __restrict__ cb,
                                                 float* __restrict__ hbuf)
{
    int idx = blockIdx.x * 256 + threadIdx.x;   // over SEQ*INTER, c fastest
    int c = idx % INTER;
    int s = idx / INTER;
    float acc = cb[c];
#pragma unroll
    for (int k = 0; k < 4; ++k) {
        int sp = s + k - 3;
        if (sp >= 0)
            acc = fmaf(proj[(size_t)sp * (2 * INTER) + c], cw[k * INTER + c], acc);
    }
    hbuf[idx] = siluf_(acc);
}

// ---------------------------------------------------------------------------
// h @ W_x  (K split into 8 chunks of 256) -> partials[chunk][SEQ][96]
// ---------------------------------------------------------------------------
__global__ __launch_bounds__(256) void gemm_hwx(const float* __restrict__ hbuf,
                                                const float* __restrict__ Wx,
                                                float* __restrict__ partials)
{
    __shared__ float hst[16][64];   // transposed h tile
    __shared__ float wxs[16][96];

    const int tid = threadIdx.x;
    const int tx = tid % 16;        // 16 col groups of 6
    const int ty = tid / 16;        // 16 row groups of 4
    const int m0 = blockIdx.x * 64;
    const int kc0 = blockIdx.y * 256;

    float acc[4][6];
#pragma unroll
    for (int i = 0; i < 4; ++i)
#pragma unroll
        for (int j = 0; j < 6; ++j) acc[i][j] = 0.0f;

    for (int kt = 0; kt < 16; ++kt) {
        const int k0 = kc0 + kt * 16;
        {
            int row = tid >> 2, seg = tid & 3;
            float4 v = *(const float4*)&hbuf[(size_t)(m0 + row) * INTER + k0 + seg * 4];
            hst[seg * 4 + 0][row] = v.x;
            hst[seg * 4 + 1][row] = v.y;
            hst[seg * 4 + 2][row] = v.z;
            hst[seg * 4 + 3][row] = v.w;
        }
        for (int j = tid; j < 16 * 96; j += 256)
            wxs[j / 96][j % 96] = Wx[(size_t)(k0 + j / 96) * NP + (j % 96)];
        __syncthreads();

#pragma unroll
        for (int k = 0; k < 16; ++k) {
            float a[4], b[6];
#pragma unroll
            for (int i = 0; i < 4; ++i) a[i] = hst[k][ty * 4 + i];
#pragma unroll
            for (int j = 0; j < 6; ++j) b[j] = wxs[k][tx * 6 + j];
#pragma unroll
            for (int i = 0; i < 4; ++i)
#pragma unroll
                for (int j = 0; j < 6; ++j)
                    acc[i][j] = fmaf(a[i], b[j], acc[i][j]);
        }
        __syncthreads();
    }

    float* P = partials + (size_t)blockIdx.y * (SEQ * NP);
#pragma unroll
    for (int i = 0; i < 4; ++i)
#pragma unroll
        for (int j = 0; j < 6; ++j)
            P[(size_t)(m0 + ty * 4 + i) * NP + tx * 6 + j] = acc[i][j];
}

__global__ __launch_bounds__(256) void reduce_partials(const float* __restrict__ partials,
                                                       float* __restrict__ ssm_p)
{
    int i = blockIdx.x * 256 + threadIdx.x;
    if (i < SEQ * NP) {
        float a = 0.0f;
#pragma unroll
        for (int c = 0; c < 8; ++c) a += partials[(size_t)c * (SEQ * NP) + i];
        ssm_p[i] = a;
    }
}

// ---------------------------------------------------------------------------
// dt = softplus(ts @ W_dt + b_dt); ts = ssm_p[:, :64]
// ---------------------------------------------------------------------------
__global__ __launch_bounds__(256) void dt_gemm(const float* __restrict__ ssm_p,
                                               const float* __restrict__ Wdt,
                                               const float* __restrict__ bdt,
                                               float* __restrict__ dtb)
{
    __shared__ float tss[16][64];
    const int tid = threadIdx.x;
    const int s0 = blockIdx.y * 16;
    const int n = blockIdx.x * 256 + tid;

    for (int j = tid; j < 16 * 64; j += 256) {
        int r = j >> 6, k = j & 63;
        tss[r][k] = ssm_p[(size_t)(s0 + r) * NP + k];
    }
    __syncthreads();

    float bv = bdt[n];
    float acc[16];
#pragma unroll
    for (int r = 0; r < 16; ++r) acc[r] = bv;

    for (int k = 0; k < 64; ++k) {
        float w = Wdt[(size_t)k * INTER + n];
#pragma unroll
        for (int r = 0; r < 16; ++r) acc[r] = fmaf(tss[r][k], w, acc[r]);
    }
#pragma unroll
    for (int r = 0; r < 16; ++r)
        dtb[(size_t)(s0 + r) * INTER + n] = softplusf_(acc[r]);
}

// ---------------------------------------------------------------------------
// Chunked parallel scan for the SSM.
//   state[s] = dA[s]*state[s-1] + dBu[s]  is affine -> over a chunk:
//   state_end = P*state_start + S_local,  P = prod dA, S_local from zero init.
// pass1: per (h, chunk) compute S_local[16], P[16]        (no cross-lane ops)
// pass2: per (h,d) tiny sequential scan over 64 chunks -> carry_in per chunk
// pass3: per (h, chunk) re-run recurrence from carry_in, emit
//        y = (state . C) + h*D, fused with *silu(gate)
// ---------------------------------------------------------------------------
__global__ __launch_bounds__(256) void ssm_pass1(const float* __restrict__ dtb,
                                                 const float* __restrict__ hbuf,
                                                 const float* __restrict__ ssm_p,
                                                 const float* __restrict__ A_log,
                                                 float* __restrict__ Sbuf,
                                                 float* __restrict__ Pbuf)
{
    const int h = blockIdx.x * 256 + threadIdx.x;
    const int c = blockIdx.y;
    const int s0 = c * LCH;

    __shared__ float Bs[LCH][DST];
    for (int j = threadIdx.x; j < LCH * DST; j += 256) {
        int r = j >> 4, dd = j & 15;
        Bs[r][dd] = ssm_p[(size_t)(s0 + r) * NP + DTR + dd];
    }
    __syncthreads();

    float A[DST], st[DST], P[DST];
#pragma unroll
    for (int d = 0; d < DST; ++d) {
        A[d] = -__expf(A_log[(size_t)h * DST + d]);
        st[d] = 0.0f;
        P[d] = 1.0f;
    }

    for (int r = 0; r < LCH; ++r) {
        float dtv = dtb[(size_t)(s0 + r) * INTER + h];
        float hv  = hbuf[(size_t)(s0 + r) * INTER + h];
        float dh = dtv * hv;
#pragma unroll
        for (int d = 0; d < DST; ++d) {
            float da = __expf(dtv * A[d]);
            st[d] = fmaf(da, st[d], dh * Bs[r][d]);
            P[d] *= da;
        }
    }

    size_t base = ((size_t)c * INTER + h) * DST;
#pragma unroll
    for (int d = 0; d < DST; d += 4) {
        *(float4*)&Sbuf[base + d] = make_float4(st[d], st[d+1], st[d+2], st[d+3]);
        *(float4*)&Pbuf[base + d] = make_float4(P[d], P[d+1], P[d+2], P[d+3]);
    }
}

__global__ __launch_bounds__(256) void ssm_pass2(const float* __restrict__ Sbuf,
                                                 const float* __restrict__ Pbuf,
                                                 float* __restrict__ Cin)
{
    int i = blockIdx.x * 256 + threadIdx.x;     // over INTER*DST = 32768
    float carry = 0.0f;
    for (int c = 0; c < NC; ++c) {
        size_t idx = (size_t)c * (INTER * DST) + i;
        Cin[idx] = carry;
        carry = fmaf(Pbuf[idx], carry, Sbuf[idx]);
    }
}

__global__ __launch_bounds__(256) void ssm_pass3(const float* __restrict__ dtb,
                                                 const float* __restrict__ hbuf,
                                                 const float* __restrict__ ssm_p,
                                                 const float* __restrict__ proj,
                                                 const float* __restrict__ A_log,
                                                 const float* __restrict__ Dvec,
                                                 const float* __restrict__ Cin,
                                                 float* __restrict__ ybuf)
{
    const int h = blockIdx.x * 256 + threadIdx.x;
    const int c = blockIdx.y;
    const int s0 = c * LCH;

    __shared__ float Bs[LCH][DST];
    __shared__ float Cs[LCH][DST];
    for (int j = threadIdx.x; j < LCH * DST; j += 256) {
        int r = j >> 4, dd = j & 15;
        Bs[r][dd] = ssm_p[(size_t)(s0 + r) * NP + DTR + dd];
        Cs[r][dd] = ssm_p[(size_t)(s0 + r) * NP + DTR + DST + dd];
    }
    __syncthreads();

    float A[DST], st[DST];
    size_t base = ((size_t)c * INTER + h) * DST;
#pragma unroll
    for (int d = 0; d < DST; ++d) {
        A[d] = -__expf(A_log[(size_t)h * DST + d]);
        st[d] = Cin[base + d];
    }
    const float Dv = Dvec[h];

    for (int r = 0; r < LCH; ++r) {
        float dtv = dtb[(size_t)(s0 + r) * INTER + h];
        float hv  = hbuf[(size_t)(s0 + r) * INTER + h];
        float g   = proj[(size_t)(s0 + r) * (2 * INTER) + INTER + h];
        float dh = dtv * hv;
        float y = 0.0f;
#pragma unroll
        for (int d = 0; d < DST; ++d) {
            float da = __expf(dtv * A[d]);
            st[d] = fmaf(da, st[d], dh * Bs[r][d]);
            y = fmaf(st[d], Cs[r][d], y);
        }
        y = fmaf(hv, Dv, y);
        ybuf[(size_t)(s0 + r) * INTER + h] = y * siluf_(g);
    }
}

// ---------------------------------------------------------------------------
extern "C" void kernel_launch(void* const* d_in, const int* in_sizes, int n_in,
                              void* d_out, int out_size, void* d_ws, size_t ws_size,
                              hipStream_t stream)
{
    const float* x      = (const float*)d_in[0];
    const float* W_in   = (const float*)d_in[1];
    const float* conv_w = (const float*)d_in[2];
    const float* conv_b = (const float*)d_in[3];
    const float* W_x    = (const float*)d_in[4];
    const float* W_dt   = (const float*)d_in[5];
    const float* b_dt   = (const float*)d_in[6];
    const float* A_log  = (const float*)d_in[7];
    const float* Dv     = (const float*)d_in[8];
    const float* W_out  = (const float*)d_in[9];
    float* out = (float*)d_out;

    float* ws    = (float*)d_ws;
    float* proj  = ws;                             // SEQ*4096
    float* hbuf  = proj  + (size_t)SEQ * 4096;     // SEQ*INTER
    float* dtb   = hbuf  + (size_t)SEQ * INTER;    // SEQ*INTER
    float* ybuf  = dtb   + (size_t)SEQ * INTER;    // SEQ*INTER
    float* ssm_p = ybuf  + (size_t)SEQ * INTER;    // SEQ*NP
    float* parts = ssm_p + (size_t)SEQ * NP;       // 8*SEQ*NP
    float* Sbuf  = parts + (size_t)8 * SEQ * NP;   // NC*INTER*DST
    float* Pbuf  = Sbuf  + (size_t)NC * INTER * DST;
    float* Cin   = Pbuf  + (size_t)NC * INTER * DST;

    // 1) proj = x @ W_in   (2048 x 4096 x 1024)
    gemm_f32<128, 128, 16, 8, 8><<<dim3(4096 / 128, SEQ / 128), 256, 0, stream>>>(
        x, W_in, proj, SEQ, 2 * INTER, HID);

    // 2) h = silu(causal depthwise conv(raw) + b)
    conv_silu<<<(SEQ * INTER) / 256, 256, 0, stream>>>(proj, conv_w, conv_b, hbuf);

    // 3) ssm_p = h @ W_x   (split-K=8 + reduce)
    gemm_hwx<<<dim3(SEQ / 64, 8), 256, 0, stream>>>(hbuf, W_x, parts);
    reduce_partials<<<(SEQ * NP + 255) / 256, 256, 0, stream>>>(parts, ssm_p);

    // 4) dt = softplus(ts @ W_dt + b_dt)
    dt_gemm<<<dim3(INTER / 256, SEQ / 16), 256, 0, stream>>>(ssm_p, W_dt, b_dt, dtb);

    // 5) chunked SSM scan, fused epilogue
    ssm_pass1<<<dim3(INTER / 256, NC), 256, 0, stream>>>(dtb, hbuf, ssm_p, A_log, Sbuf, Pbuf);
    ssm_pass2<<<(INTER * DST) / 256, 256, 0, stream>>>(Sbuf, Pbuf, Cin);
    ssm_pass3<<<dim3(INTER / 256, NC), 256, 0, stream>>>(dtb, hbuf, ssm_p, proj, A_log, Dv, Cin, ybuf);

    // 6) out = y @ W_out   (2048 x 1024 x 2048)
    gemm_f32<64, 128, 16, 4, 8><<<dim3(HID / 128, SEQ / 64), 256, 0, stream>>>(
        ybuf, W_out, out, SEQ, HID, INTER);
}

// Round 3
// 233.151 us; speedup vs baseline: 5.0360x; 2.3535x over previous
//
#include <hip/hip_runtime.h>
#include <math.h>

#define SEQ   2048
#define HID   1024
#define INTER 2048
#define DST   16
#define DTR   64
#define NP    96   // DTR + 2*DST
#define NC    64   // scan chunks
#define LCH   32   // steps per chunk (NC*LCH == SEQ)

typedef _Float16 f16;
typedef _Float16 f16x8 __attribute__((ext_vector_type(8)));
typedef _Float16 f16x4v __attribute__((ext_vector_type(4)));
typedef float f32x4 __attribute__((ext_vector_type(4)));

__device__ __forceinline__ float sigmoidf_(float x) { return 1.0f / (1.0f + expf(-x)); }
__device__ __forceinline__ float siluf_(float x)    { return x * sigmoidf_(x); }
__device__ __forceinline__ float softplusf_(float x){ return (x > 20.0f) ? x : log1pf(expf(x)); }

// ---------------------------------------------------------------------------
// f32 -> f16 elementwise (n multiple of 1024)
// ---------------------------------------------------------------------------
__global__ __launch_bounds__(256) void cvt_f16(const float* __restrict__ in,
                                               f16* __restrict__ out)
{
    int i = (blockIdx.x * 256 + threadIdx.x) * 4;
    float4 v = *(const float4*)&in[i];
    f16x4v o;
    o.x = (f16)v.x; o.y = (f16)v.y; o.z = (f16)v.z; o.w = (f16)v.w;
    *(f16x4v*)&out[i] = o;
}

// ---------------------------------------------------------------------------
// W[K][N] f32 -> Wt[N][K] f16, 32x32 tiles (both sides coalesced)
// ---------------------------------------------------------------------------
__global__ __launch_bounds__(256) void transpose_f16(const float* __restrict__ W,
                                                     f16* __restrict__ Wt,
                                                     int K, int N)
{
    __shared__ float t[32][33];
    const int n0 = blockIdx.x * 32, k0 = blockIdx.y * 32;
    const int j = threadIdx.x & 31, i0 = threadIdx.x >> 5;   // i0: 0..7
#pragma unroll
    for (int r = 0; r < 4; ++r)
        t[i0 + r * 8][j] = W[(size_t)(k0 + i0 + r * 8) * N + n0 + j];
    __syncthreads();
#pragma unroll
    for (int r = 0; r < 4; ++r)
        Wt[(size_t)(n0 + i0 + r * 8) * K + k0 + j] = (f16)t[j][i0 + r * 8];
}

// ---------------------------------------------------------------------------
// MFMA f16 GEMM: C[M,N] f32 = Ah[M,K] f16 @ Bt[N,K]^T f16.
// m97 structure: BK=64, 4 waves (2x2), global_load_lds width 16, linear LDS.
// ---------------------------------------------------------------------------
template<int BM, int BN, int KK>
__global__ __launch_bounds__(256) void gemm_f16mfma(const f16* __restrict__ Ah,
                                                    const f16* __restrict__ Bt,
                                                    float* __restrict__ C,
                                                    int N)
{
    constexpr int BK = 64;
    __shared__ __align__(16) f16 As[BM * BK];
    __shared__ __align__(16) f16 Bs[BN * BK];

    const int tid = threadIdx.x;
    const int wid = tid >> 6, lane = tid & 63;
    const int wr = wid >> 1, wc = wid & 1;
    const int m0 = blockIdx.y * BM, n0 = blockIdx.x * BN;
    const int l15 = lane & 15, lhi = lane >> 4;

    constexpr int MR = BM / 32;   // 16-row frags per wave
    constexpr int NR = BN / 32;

    f32x4 acc[MR][NR] = {};

    for (int k0 = 0; k0 < KK; k0 += BK) {
        // ---- stage A,B tiles: 1024B per wave-instruction, linear LDS ----
        constexpr int CA = BM * BK * 2 / 1024;   // 1KB chunks of A
#pragma unroll
        for (int c0 = 0; c0 < CA; c0 += 4) {
            int c = c0 + wid;
            int e = c * 64 + lane;               // 16B-unit index; 8 per row
            int row = e >> 3, seg = e & 7;
            __builtin_amdgcn_global_load_lds(
                (const __attribute__((address_space(1))) unsigned int*)
                    (Ah + (size_t)(m0 + row) * KK + k0 + seg * 8),
                (__attribute__((address_space(3))) unsigned int*)(As + c * 512),
                16, 0, 0);
        }
        constexpr int CB = BN * BK * 2 / 1024;
#pragma unroll
        for (int c0 = 0; c0 < CB; c0 += 4) {
            int c = c0 + wid;
            int e = c * 64 + lane;
            int row = e >> 3, seg = e & 7;
            __builtin_amdgcn_global_load_lds(
                (const __attribute__((address_space(1))) unsigned int*)
                    (Bt + (size_t)(n0 + row) * KK + k0 + seg * 8),
                (__attribute__((address_space(3))) unsigned int*)(Bs + c * 512),
                16, 0, 0);
        }
        __syncthreads();   // compiler drains vmcnt(0) before barrier

#pragma unroll
        for (int kk = 0; kk < BK; kk += 32) {
            f16x8 af[MR], bf[NR];
#pragma unroll
            for (int i = 0; i < MR; ++i)
                af[i] = *(const f16x8*)&As[(wr * (BM / 2) + i * 16 + l15) * BK + kk + lhi * 8];
#pragma unroll
            for (int n = 0; n < NR; ++n)
                bf[n] = *(const f16x8*)&Bs[(wc * (BN / 2) + n * 16 + l15) * BK + kk + lhi * 8];
#pragma unroll
            for (int i = 0; i < MR; ++i)
#pragma unroll
                for (int n = 0; n < NR; ++n)
                    acc[i][n] = __builtin_amdgcn_mfma_f32_16x16x32_f16(af[i], bf[n], acc[i][n], 0, 0, 0);
        }
        __syncthreads();
    }

    // epilogue: verified C/D map — col = lane&15, row = (lane>>4)*4 + reg
#pragma unroll
    for (int i = 0; i < MR; ++i)
#pragma unroll
        for (int n = 0; n < NR; ++n)
#pragma unroll
            for (int r = 0; r < 4; ++r)
                C[(size_t)(m0 + wr * (BM / 2) + i * 16 + lhi * 4 + r) * N
                  + n0 + wc * (BN / 2) + n * 16 + l15] = acc[i][n][r];
}

// ---------------------------------------------------------------------------
// Depthwise causal conv (K=4) + bias + SiLU.  raw = proj[:, :INTER]
// ---------------------------------------------------------------------------
__global__ __launch_bounds__(256) void conv_silu(const float* __restrict__ proj,
                                                 const float* __restrict__ cw,
                                                 const float* __restrict__ cb,
                                                 float* __restrict__ hbuf)
{
    int idx = blockIdx.x * 256 + threadIdx.x;   // over SEQ*INTER, c fastest
    int c = idx % INTER;
    int s = idx / INTER;
    float acc = cb[c];
#pragma unroll
    for (int k = 0; k < 4; ++k) {
        int sp = s + k - 3;
        if (sp >= 0)
            acc = fmaf(proj[(size_t)sp * (2 * INTER) + c], cw[k * INTER + c], acc);
    }
    hbuf[idx] = siluf_(acc);
}

// ---------------------------------------------------------------------------
// h @ W_x  (K split into 8 chunks of 256) -> partials[chunk][SEQ][96]
// ---------------------------------------------------------------------------
__global__ __launch_bounds__(256) void gemm_hwx(const float* __restrict__ hbuf,
                                                const float* __restrict__ Wx,
                                                float* __restrict__ partials)
{
    __shared__ float hst[16][64];   // transposed h tile
    __shared__ float wxs[16][96];

    const int tid = threadIdx.x;
    const int tx = tid % 16;        // 16 col groups of 6
    const int ty = tid / 16;        // 16 row groups of 4
    const int m0 = blockIdx.x * 64;
    const int kc0 = blockIdx.y * 256;

    float acc[4][6];
#pragma unroll
    for (int i = 0; i < 4; ++i)
#pragma unroll
        for (int j = 0; j < 6; ++j) acc[i][j] = 0.0f;

    for (int kt = 0; kt < 16; ++kt) {
        const int k0 = kc0 + kt * 16;
        {
            int row = tid >> 2, seg = tid & 3;
            float4 v = *(const float4*)&hbuf[(size_t)(m0 + row) * INTER + k0 + seg * 4];
            hst[seg * 4 + 0][row] = v.x;
            hst[seg * 4 + 1][row] = v.y;
            hst[seg * 4 + 2][row] = v.z;
            hst[seg * 4 + 3][row] = v.w;
        }
        for (int j = tid; j < 16 * 96; j += 256)
            wxs[j / 96][j % 96] = Wx[(size_t)(k0 + j / 96) * NP + (j % 96)];
        __syncthreads();

#pragma unroll
        for (int k = 0; k < 16; ++k) {
            float a[4], b[6];
#pragma unroll
            for (int i = 0; i < 4; ++i) a[i] = hst[k][ty * 4 + i];
#pragma unroll
            for (int j = 0; j < 6; ++j) b[j] = wxs[k][tx * 6 + j];
#pragma unroll
            for (int i = 0; i < 4; ++i)
#pragma unroll
                for (int j = 0; j < 6; ++j)
                    acc[i][j] = fmaf(a[i], b[j], acc[i][j]);
        }
        __syncthreads();
    }

    float* P = partials + (size_t)blockIdx.y * (SEQ * NP);
#pragma unroll
    for (int i = 0; i < 4; ++i)
#pragma unroll
        for (int j = 0; j < 6; ++j)
            P[(size_t)(m0 + ty * 4 + i) * NP + tx * 6 + j] = acc[i][j];
}

__global__ __launch_bounds__(256) void reduce_partials(const float* __restrict__ partials,
                                                       float* __restrict__ ssm_p)
{
    int i = blockIdx.x * 256 + threadIdx.x;
    if (i < SEQ * NP) {
        float a = 0.0f;
#pragma unroll
        for (int c = 0; c < 8; ++c) a += partials[(size_t)c * (SEQ * NP) + i];
        ssm_p[i] = a;
    }
}

// ---------------------------------------------------------------------------
// dt = softplus(ts @ W_dt + b_dt); ts = ssm_p[:, :64]
// ---------------------------------------------------------------------------
__global__ __launch_bounds__(256) void dt_gemm(const float* __restrict__ ssm_p,
                                               const float* __restrict__ Wdt,
                                               const float* __restrict__ bdt,
                                               float* __restrict__ dtb)
{
    __shared__ float tss[16][64];
    const int tid = threadIdx.x;
    const int s0 = blockIdx.y * 16;
    const int n = blockIdx.x * 256 + tid;

    for (int j = tid; j < 16 * 64; j += 256) {
        int r = j >> 6, k = j & 63;
        tss[r][k] = ssm_p[(size_t)(s0 + r) * NP + k];
    }
    __syncthreads();

    float bv = bdt[n];
    float acc[16];
#pragma unroll
    for (int r = 0; r < 16; ++r) acc[r] = bv;

    for (int k = 0; k < 64; ++k) {
        float w = Wdt[(size_t)k * INTER + n];
#pragma unroll
        for (int r = 0; r < 16; ++r) acc[r] = fmaf(tss[r][k], w, acc[r]);
    }
#pragma unroll
    for (int r = 0; r < 16; ++r)
        dtb[(size_t)(s0 + r) * INTER + n] = softplusf_(acc[r]);
}

// ---------------------------------------------------------------------------
// Chunked parallel scan (pass1/2/3); pass3 emits y as f16 for the MFMA GEMM.
// ---------------------------------------------------------------------------
__global__ __launch_bounds__(256) void ssm_pass1(const float* __restrict__ dtb,
                                                 const float* __restrict__ hbuf,
                                                 const float* __restrict__ ssm_p,
                                                 const float* __restrict__ A_log,
                                                 float* __restrict__ Sbuf,
                                                 float* __restrict__ Pbuf)
{
    const int h = blockIdx.x * 256 + threadIdx.x;
    const int c = blockIdx.y;
    const int s0 = c * LCH;

    __shared__ float Bs[LCH][DST];
    for (int j = threadIdx.x; j < LCH * DST; j += 256) {
        int r = j >> 4, dd = j & 15;
        Bs[r][dd] = ssm_p[(size_t)(s0 + r) * NP + DTR + dd];
    }
    __syncthreads();

    float A[DST], st[DST], P[DST];
#pragma unroll
    for (int d = 0; d < DST; ++d) {
        A[d] = -__expf(A_log[(size_t)h * DST + d]);
        st[d] = 0.0f;
        P[d] = 1.0f;
    }

    for (int r = 0; r < LCH; ++r) {
        float dtv = dtb[(size_t)(s0 + r) * INTER + h];
        float hv  = hbuf[(size_t)(s0 + r) * INTER + h];
        float dh = dtv * hv;
#pragma unroll
        for (int d = 0; d < DST; ++d) {
            float da = __expf(dtv * A[d]);
            st[d] = fmaf(da, st[d], dh * Bs[r][d]);
            P[d] *= da;
        }
    }

    size_t base = ((size_t)c * INTER + h) * DST;
#pragma unroll
    for (int d = 0; d < DST; d += 4) {
        *(float4*)&Sbuf[base + d] = make_float4(st[d], st[d+1], st[d+2], st[d+3]);
        *(float4*)&Pbuf[base + d] = make_float4(P[d], P[d+1], P[d+2], P[d+3]);
    }
}

__global__ __launch_bounds__(256) void ssm_pass2(const float* __restrict__ Sbuf,
                                                 const float* __restrict__ Pbuf,
                                                 float* __restrict__ Cin)
{
    int i = blockIdx.x * 256 + threadIdx.x;     // over INTER*DST = 32768
    float carry = 0.0f;
    for (int c = 0; c < NC; ++c) {
        size_t idx = (size_t)c * (INTER * DST) + i;
        Cin[idx] = carry;
        carry = fmaf(Pbuf[idx], carry, Sbuf[idx]);
    }
}

__global__ __launch_bounds__(256) void ssm_pass3(const float* __restrict__ dtb,
                                                 const float* __restrict__ hbuf,
                                                 const float* __restrict__ ssm_p,
                                                 const float* __restrict__ proj,
                                                 const float* __restrict__ A_log,
                                                 const float* __restrict__ Dvec,
                                                 const float* __restrict__ Cin,
                                                 f16* __restrict__ yh)
{
    const int h = blockIdx.x * 256 + threadIdx.x;
    const int c = blockIdx.y;
    const int s0 = c * LCH;

    __shared__ float Bs[LCH][DST];
    __shared__ float Cs[LCH][DST];
    for (int j = threadIdx.x; j < LCH * DST; j += 256) {
        int r = j >> 4, dd = j & 15;
        Bs[r][dd] = ssm_p[(size_t)(s0 + r) * NP + DTR + dd];
        Cs[r][dd] = ssm_p[(size_t)(s0 + r) * NP + DTR + DST + dd];
    }
    __syncthreads();

    float A[DST], st[DST];
    size_t base = ((size_t)c * INTER + h) * DST;
#pragma unroll
    for (int d = 0; d < DST; ++d) {
        A[d] = -__expf(A_log[(size_t)h * DST + d]);
        st[d] = Cin[base + d];
    }
    const float Dv = Dvec[h];

    for (int r = 0; r < LCH; ++r) {
        float dtv = dtb[(size_t)(s0 + r) * INTER + h];
        float hv  = hbuf[(size_t)(s0 + r) * INTER + h];
        float g   = proj[(size_t)(s0 + r) * (2 * INTER) + INTER + h];
        float dh = dtv * hv;
        float y = 0.0f;
#pragma unroll
        for (int d = 0; d < DST; ++d) {
            float da = __expf(dtv * A[d]);
            st[d] = fmaf(da, st[d], dh * Bs[r][d]);
            y = fmaf(st[d], Cs[r][d], y);
        }
        y = fmaf(hv, Dv, y);
        yh[(size_t)(s0 + r) * INTER + h] = (f16)(y * siluf_(g));
    }
}

// ---------------------------------------------------------------------------
extern "C" void kernel_launch(void* const* d_in, const int* in_sizes, int n_in,
                              void* d_out, int out_size, void* d_ws, size_t ws_size,
                              hipStream_t stream)
{
    const float* x      = (const float*)d_in[0];
    const float* W_in   = (const float*)d_in[1];
    const float* conv_w = (const float*)d_in[2];
    const float* conv_b = (const float*)d_in[3];
    const float* W_x    = (const float*)d_in[4];
    const float* W_dt   = (const float*)d_in[5];
    const float* b_dt   = (const float*)d_in[6];
    const float* A_log  = (const float*)d_in[7];
    const float* Dv     = (const float*)d_in[8];
    const float* W_out  = (const float*)d_in[9];
    float* out = (float*)d_out;

    float* ws = (float*)d_ws;
    // f32 regions (element offsets)
    float* proj  = ws;                         // 8388608
    float* hbuf  = ws + 8388608;               // 4194304
    float* dtb   = ws + 12582912;              // 4194304
    float* ssm_p = ws + 16777216;              // 196608
    float* parts = ws + 16973824;              // 1572864
    float* Sbuf  = ws + 18546688;              // 2097152
    float* Pbuf  = ws + 20643840;              // 2097152
    float* Cin   = ws + 22740992;              // 2097152
    // f16 region R1 (phase 1 only) aliases Sbuf/Pbuf space (dead until pass1)
    f16* xh      = (f16*)(ws + 18546688);      // 2M halves
    f16* W_in_t  = (f16*)(ws + 19595264);      // 4M halves
    // f16 region R3 (phases 5-6), after Cin
    f16* yh      = (f16*)(ws + 24838144);      // 4M halves
    f16* W_out_t = (f16*)(ws + 26935296);      // 2M halves

    // 0) conversions for MFMA operands
    cvt_f16<<<(SEQ * HID) / 1024, 256, 0, stream>>>(x, xh);
    transpose_f16<<<dim3(4096 / 32, HID / 32), 256, 0, stream>>>(W_in, W_in_t, HID, 2 * INTER);
    transpose_f16<<<dim3(HID / 32, INTER / 32), 256, 0, stream>>>(W_out, W_out_t, INTER, HID);

    // 1) proj = x @ W_in   (2048 x 4096 x 1024), f16 MFMA
    gemm_f16mfma<128, 128, HID><<<dim3(4096 / 128, SEQ / 128), 256, 0, stream>>>(
        xh, W_in_t, proj, 2 * INTER);

    // 2) h = silu(causal depthwise conv(raw) + b)
    conv_silu<<<(SEQ * INTER) / 256, 256, 0, stream>>>(proj, conv_w, conv_b, hbuf);

    // 3) ssm_p = h @ W_x   (split-K=8 + reduce)
    gemm_hwx<<<dim3(SEQ / 64, 8), 256, 0, stream>>>(hbuf, W_x, parts);
    reduce_partials<<<(SEQ * NP + 255) / 256, 256, 0, stream>>>(parts, ssm_p);

    // 4) dt = softplus(ts @ W_dt + b_dt)
    dt_gemm<<<dim3(INTER / 256, SEQ / 16), 256, 0, stream>>>(ssm_p, W_dt, b_dt, dtb);

    // 5) chunked SSM scan, fused epilogue -> y in f16
    ssm_pass1<<<dim3(INTER / 256, NC), 256, 0, stream>>>(dtb, hbuf, ssm_p, A_log, Sbuf, Pbuf);
    ssm_pass2<<<(INTER * DST) / 256, 256, 0, stream>>>(Sbuf, Pbuf, Cin);
    ssm_pass3<<<dim3(INTER / 256, NC), 256, 0, stream>>>(dtb, hbuf, ssm_p, proj, A_log, Dv, Cin, yh);

    // 6) out = y @ W_out   (2048 x 1024 x 2048), f16 MFMA, 64x128 tile
    gemm_f16mfma<64, 128, INTER><<<dim3(HID / 128, SEQ / 64), 256, 0, stream>>>(
        yh, W_out_t, out, HID);
}

// Round 4
// 195.948 us; speedup vs baseline: 5.9922x; 1.1899x over previous
//
#include <hip/hip_runtime.h>
#include <math.h>

#define SEQ   2048
#define HID   1024
#define INTER 2048
#define DST   16
#define DTR   64
#define NP    96   // DTR + 2*DST
#define NC    64   // scan chunks
#define LCH   32   // steps per chunk (NC*LCH == SEQ)
#define KS    16   // split-K factor for h @ W_x

typedef _Float16 f16;
typedef _Float16 f16x8 __attribute__((ext_vector_type(8)));
typedef _Float16 f16x4v __attribute__((ext_vector_type(4)));
typedef float f32x4 __attribute__((ext_vector_type(4)));

__device__ __forceinline__ float sigmoidf_(float x) { return 1.0f / (1.0f + expf(-x)); }
__device__ __forceinline__ float siluf_(float x)    { return x * sigmoidf_(x); }
__device__ __forceinline__ float softplusf_(float x){ return (x > 20.0f) ? x : log1pf(expf(x)); }

// ---------------------------------------------------------------------------
// f32 -> f16 elementwise (n multiple of 1024)
// ---------------------------------------------------------------------------
__global__ __launch_bounds__(256) void cvt_f16(const float* __restrict__ in,
                                               f16* __restrict__ out)
{
    int i = (blockIdx.x * 256 + threadIdx.x) * 4;
    float4 v = *(const float4*)&in[i];
    f16x4v o;
    o.x = (f16)v.x; o.y = (f16)v.y; o.z = (f16)v.z; o.w = (f16)v.w;
    *(f16x4v*)&out[i] = o;
}

// ---------------------------------------------------------------------------
// W[K][N] f32 -> Wt[N][K] f16, 32x32 tiles (both sides coalesced)
// ---------------------------------------------------------------------------
__global__ __launch_bounds__(256) void transpose_f16(const float* __restrict__ W,
                                                     f16* __restrict__ Wt,
                                                     int K, int N)
{
    __shared__ float t[32][33];
    const int n0 = blockIdx.x * 32, k0 = blockIdx.y * 32;
    const int j = threadIdx.x & 31, i0 = threadIdx.x >> 5;   // i0: 0..7
#pragma unroll
    for (int r = 0; r < 4; ++r)
        t[i0 + r * 8][j] = W[(size_t)(k0 + i0 + r * 8) * N + n0 + j];
    __syncthreads();
#pragma unroll
    for (int r = 0; r < 4; ++r)
        Wt[(size_t)(n0 + i0 + r * 8) * K + k0 + j] = (f16)t[j][i0 + r * 8];
}

// ---------------------------------------------------------------------------
// MFMA f16 GEMM: C[M,N] f32 = Ah[M,K] f16 @ Bt[N,K]^T f16.
// m97 structure: BK=64, 4 waves (2x2), global_load_lds width 16, linear LDS.
// ---------------------------------------------------------------------------
template<int BM, int BN, int KK>
__global__ __launch_bounds__(256) void gemm_f16mfma(const f16* __restrict__ Ah,
                                                    const f16* __restrict__ Bt,
                                                    float* __restrict__ C,
                                                    int N)
{
    constexpr int BK = 64;
    __shared__ __align__(16) f16 As[BM * BK];
    __shared__ __align__(16) f16 Bs[BN * BK];

    const int tid = threadIdx.x;
    const int wid = tid >> 6, lane = tid & 63;
    const int wr = wid >> 1, wc = wid & 1;
    const int m0 = blockIdx.y * BM, n0 = blockIdx.x * BN;
    const int l15 = lane & 15, lhi = lane >> 4;

    constexpr int MR = BM / 32;   // 16-row frags per wave
    constexpr int NR = BN / 32;

    f32x4 acc[MR][NR] = {};

    for (int k0 = 0; k0 < KK; k0 += BK) {
        constexpr int CA = BM * BK * 2 / 1024;   // 1KB chunks of A
#pragma unroll
        for (int c0 = 0; c0 < CA; c0 += 4) {
            int c = c0 + wid;
            int e = c * 64 + lane;
            int row = e >> 3, seg = e & 7;
            __builtin_amdgcn_global_load_lds(
                (const __attribute__((address_space(1))) unsigned int*)
                    (Ah + (size_t)(m0 + row) * KK + k0 + seg * 8),
                (__attribute__((address_space(3))) unsigned int*)(As + c * 512),
                16, 0, 0);
        }
        constexpr int CB = BN * BK * 2 / 1024;
#pragma unroll
        for (int c0 = 0; c0 < CB; c0 += 4) {
            int c = c0 + wid;
            int e = c * 64 + lane;
            int row = e >> 3, seg = e & 7;
            __builtin_amdgcn_global_load_lds(
                (const __attribute__((address_space(1))) unsigned int*)
                    (Bt + (size_t)(n0 + row) * KK + k0 + seg * 8),
                (__attribute__((address_space(3))) unsigned int*)(Bs + c * 512),
                16, 0, 0);
        }
        __syncthreads();

#pragma unroll
        for (int kk = 0; kk < BK; kk += 32) {
            f16x8 af[MR], bf[NR];
#pragma unroll
            for (int i = 0; i < MR; ++i)
                af[i] = *(const f16x8*)&As[(wr * (BM / 2) + i * 16 + l15) * BK + kk + lhi * 8];
#pragma unroll
            for (int n = 0; n < NR; ++n)
                bf[n] = *(const f16x8*)&Bs[(wc * (BN / 2) + n * 16 + l15) * BK + kk + lhi * 8];
#pragma unroll
            for (int i = 0; i < MR; ++i)
#pragma unroll
                for (int n = 0; n < NR; ++n)
                    acc[i][n] = __builtin_amdgcn_mfma_f32_16x16x32_f16(af[i], bf[n], acc[i][n], 0, 0, 0);
        }
        __syncthreads();
    }

    // C/D map: col = lane&15, row = (lane>>4)*4 + reg
#pragma unroll
    for (int i = 0; i < MR; ++i)
#pragma unroll
        for (int n = 0; n < NR; ++n)
#pragma unroll
            for (int r = 0; r < 4; ++r)
                C[(size_t)(m0 + wr * (BM / 2) + i * 16 + lhi * 4 + r) * N
                  + n0 + wc * (BN / 2) + n * 16 + l15] = acc[i][n][r];
}

// ---------------------------------------------------------------------------
// h @ W_x split-K MFMA: partials[ks][SEQ][96] = h[:, ks*128:+128] @ WxT^T
// ---------------------------------------------------------------------------
__global__ __launch_bounds__(256) void hwx_mfma(const f16* __restrict__ hh,
                                                const f16* __restrict__ WxT,
                                                float* __restrict__ partials)
{
    constexpr int BM = 128, BN = 96, BK = 64;
    __shared__ __align__(16) f16 As[BM * BK];
    __shared__ __align__(16) f16 Bs[BN * BK];

    const int tid = threadIdx.x;
    const int wid = tid >> 6, lane = tid & 63;
    const int wr = wid >> 1, wc = wid & 1;
    const int m0 = blockIdx.x * BM;
    const int ks = blockIdx.y;
    const int l15 = lane & 15, lhi = lane >> 4;

    constexpr int MR = 4, NR = 3;   // 64 rows, 48 cols per wave
    f32x4 acc[MR][NR] = {};

    for (int k0 = ks * 128; k0 < ks * 128 + 128; k0 += BK) {
#pragma unroll
        for (int c0 = 0; c0 < 16; c0 += 4) {            // A: 16 KB
            int c = c0 + wid;
            int e = c * 64 + lane;
            int row = e >> 3, seg = e & 7;
            __builtin_amdgcn_global_load_lds(
                (const __attribute__((address_space(1))) unsigned int*)
                    (hh + (size_t)(m0 + row) * INTER + k0 + seg * 8),
                (__attribute__((address_space(3))) unsigned int*)(As + c * 512),
                16, 0, 0);
        }
#pragma unroll
        for (int c0 = 0; c0 < 12; c0 += 4) {            // B: 12 KB (96 rows)
            int c = c0 + wid;
            int e = c * 64 + lane;
            int row = e >> 3, seg = e & 7;
            __builtin_amdgcn_global_load_lds(
                (const __attribute__((address_space(1))) unsigned int*)
                    (WxT + (size_t)row * INTER + k0 + seg * 8),
                (__attribute__((address_space(3))) unsigned int*)(Bs + c * 512),
                16, 0, 0);
        }
        __syncthreads();

#pragma unroll
        for (int kk = 0; kk < BK; kk += 32) {
            f16x8 af[MR], bf[NR];
#pragma unroll
            for (int i = 0; i < MR; ++i)
                af[i] = *(const f16x8*)&As[(wr * 64 + i * 16 + l15) * BK + kk + lhi * 8];
#pragma unroll
            for (int n = 0; n < NR; ++n)
                bf[n] = *(const f16x8*)&Bs[(wc * 48 + n * 16 + l15) * BK + kk + lhi * 8];
#pragma unroll
            for (int i = 0; i < MR; ++i)
#pragma unroll
                for (int n = 0; n < NR; ++n)
                    acc[i][n] = __builtin_amdgcn_mfma_f32_16x16x32_f16(af[i], bf[n], acc[i][n], 0, 0, 0);
        }
        __syncthreads();
    }

    float* P = partials + (size_t)ks * (SEQ * NP);
#pragma unroll
    for (int i = 0; i < MR; ++i)
#pragma unroll
        for (int n = 0; n < NR; ++n)
#pragma unroll
            for (int r = 0; r < 4; ++r)
                P[(size_t)(m0 + wr * 64 + i * 16 + lhi * 4 + r) * NP
                  + wc * 48 + n * 16 + l15] = acc[i][n][r];
}

__global__ __launch_bounds__(256) void reduce_partials(const float* __restrict__ partials,
                                                       float* __restrict__ ssm_p,
                                                       f16* __restrict__ tsh)
{
    int i = blockIdx.x * 256 + threadIdx.x;
    if (i < SEQ * NP) {
        float a = 0.0f;
#pragma unroll
        for (int c = 0; c < KS; ++c) a += partials[(size_t)c * (SEQ * NP) + i];
        ssm_p[i] = a;
        int j = i % NP;
        if (j < DTR) tsh[(size_t)(i / NP) * DTR + j] = (f16)a;
    }
}

// ---------------------------------------------------------------------------
// dt = softplus(ts @ W_dt + b_dt), f16 MFMA, K=64 single staging iteration.
// ---------------------------------------------------------------------------
__global__ __launch_bounds__(256) void dt_mfma(const f16* __restrict__ tsh,
                                               const f16* __restrict__ WdtT,
                                               const float* __restrict__ bdt,
                                               float* __restrict__ dtb)
{
    constexpr int BM = 128, BN = 128, BK = 64;
    __shared__ __align__(16) f16 As[BM * BK];
    __shared__ __align__(16) f16 Bs[BN * BK];

    const int tid = threadIdx.x;
    const int wid = tid >> 6, lane = tid & 63;
    const int wr = wid >> 1, wc = wid & 1;
    const int m0 = blockIdx.y * BM, n0 = blockIdx.x * BN;
    const int l15 = lane & 15, lhi = lane >> 4;

    constexpr int MR = 4, NR = 4;
    f32x4 acc[MR][NR] = {};

#pragma unroll
    for (int c0 = 0; c0 < 16; c0 += 4) {
        int c = c0 + wid;
        int e = c * 64 + lane;
        int row = e >> 3, seg = e & 7;
        __builtin_amdgcn_global_load_lds(
            (const __attribute__((address_space(1))) unsigned int*)
                (tsh + (size_t)(m0 + row) * DTR + seg * 8),
            (__attribute__((address_space(3))) unsigned int*)(As + c * 512),
            16, 0, 0);
        __builtin_amdgcn_global_load_lds(
            (const __attribute__((address_space(1))) unsigned int*)
                (WdtT + (size_t)(n0 + row) * DTR + seg * 8),
            (__attribute__((address_space(3))) unsigned int*)(Bs + c * 512),
            16, 0, 0);
    }
    __syncthreads();

#pragma unroll
    for (int kk = 0; kk < 64; kk += 32) {
        f16x8 af[MR], bf[NR];
#pragma unroll
        for (int i = 0; i < MR; ++i)
            af[i] = *(const f16x8*)&As[(wr * 64 + i * 16 + l15) * BK + kk + lhi * 8];
#pragma unroll
        for (int n = 0; n < NR; ++n)
            bf[n] = *(const f16x8*)&Bs[(wc * 64 + n * 16 + l15) * BK + kk + lhi * 8];
#pragma unroll
        for (int i = 0; i < MR; ++i)
#pragma unroll
            for (int n = 0; n < NR; ++n)
                acc[i][n] = __builtin_amdgcn_mfma_f32_16x16x32_f16(af[i], bf[n], acc[i][n], 0, 0, 0);
    }

#pragma unroll
    for (int i = 0; i < MR; ++i)
#pragma unroll
        for (int n = 0; n < NR; ++n) {
            int col = n0 + wc * 64 + n * 16 + l15;
            float bv = bdt[col];
#pragma unroll
            for (int r = 0; r < 4; ++r)
                dtb[(size_t)(m0 + wr * 64 + i * 16 + lhi * 4 + r) * INTER + col] =
                    softplusf_(acc[i][n][r] + bv);
        }
}

// ---------------------------------------------------------------------------
// Depthwise causal conv (K=4) + bias + SiLU, x4 vectorized; emits f32 + f16.
// ---------------------------------------------------------------------------
__global__ __launch_bounds__(256) void conv_silu(const float* __restrict__ proj,
                                                 const float* __restrict__ cw,
                                                 const float* __restrict__ cb,
                                                 float* __restrict__ hbuf,
                                                 f16* __restrict__ hh)
{
    int idx = blockIdx.x * 256 + threadIdx.x;   // over SEQ*INTER/4
    int c4 = (idx & (INTER / 4 - 1)) * 4;
    int s = idx >> 9;
    float4 acc = *(const float4*)&cb[c4];
#pragma unroll
    for (int k = 0; k < 4; ++k) {
        int sp = s + k - 3;
        if (sp >= 0) {
            float4 p = *(const float4*)&proj[(size_t)sp * (2 * INTER) + c4];
            float4 w = *(const float4*)&cw[k * INTER + c4];
            acc.x = fmaf(p.x, w.x, acc.x);
            acc.y = fmaf(p.y, w.y, acc.y);
            acc.z = fmaf(p.z, w.z, acc.z);
            acc.w = fmaf(p.w, w.w, acc.w);
        }
    }
    float4 o;
    o.x = siluf_(acc.x); o.y = siluf_(acc.y); o.z = siluf_(acc.z); o.w = siluf_(acc.w);
    *(float4*)&hbuf[(size_t)idx * 4] = o;
    f16x4v h4;
    h4.x = (f16)o.x; h4.y = (f16)o.y; h4.z = (f16)o.z; h4.w = (f16)o.w;
    *(f16x4v*)&hh[(size_t)idx * 4] = h4;
}

// ---------------------------------------------------------------------------
// Chunked parallel scan (pass1/2/3); pass3 emits y as f16 for the MFMA GEMM.
// ---------------------------------------------------------------------------
__global__ __launch_bounds__(256) void ssm_pass1(const float* __restrict__ dtb,
                                                 const float* __restrict__ hbuf,
                                                 const float* __restrict__ ssm_p,
                                                 const float* __restrict__ A_log,
                                                 float* __restrict__ Sbuf,
                                                 float* __restrict__ Pbuf)
{
    const int h = blockIdx.x * 256 + threadIdx.x;
    const int c = blockIdx.y;
    const int s0 = c * LCH;

    __shared__ float Bs[LCH][DST];
    for (int j = threadIdx.x; j < LCH * DST; j += 256) {
        int r = j >> 4, dd = j & 15;
        Bs[r][dd] = ssm_p[(size_t)(s0 + r) * NP + DTR + dd];
    }
    __syncthreads();

    float A[DST], st[DST], P[DST];
#pragma unroll
    for (int d = 0; d < DST; ++d) {
        A[d] = -__expf(A_log[(size_t)h * DST + d]);
        st[d] = 0.0f;
        P[d] = 1.0f;
    }

    for (int r = 0; r < LCH; ++r) {
        float dtv = dtb[(size_t)(s0 + r) * INTER + h];
        float hv  = hbuf[(size_t)(s0 + r) * INTER + h];
        float dh = dtv * hv;
#pragma unroll
        for (int d = 0; d < DST; ++d) {
            float da = __expf(dtv * A[d]);
            st[d] = fmaf(da, st[d], dh * Bs[r][d]);
            P[d] *= da;
        }
    }

    size_t base = ((size_t)c * INTER + h) * DST;
#pragma unroll
    for (int d = 0; d < DST; d += 4) {
        *(float4*)&Sbuf[base + d] = make_float4(st[d], st[d+1], st[d+2], st[d+3]);
        *(float4*)&Pbuf[base + d] = make_float4(P[d], P[d+1], P[d+2], P[d+3]);
    }
}

__global__ __launch_bounds__(256) void ssm_pass2(const float* __restrict__ Sbuf,
                                                 const float* __restrict__ Pbuf,
                                                 float* __restrict__ Cin)
{
    int i = blockIdx.x * 256 + threadIdx.x;     // over INTER*DST = 32768
    float carry = 0.0f;
    for (int c = 0; c < NC; ++c) {
        size_t idx = (size_t)c * (INTER * DST) + i;
        Cin[idx] = carry;
        carry = fmaf(Pbuf[idx], carry, Sbuf[idx]);
    }
}

__global__ __launch_bounds__(256) void ssm_pass3(const float* __restrict__ dtb,
                                                 const float* __restrict__ hbuf,
                                                 const float* __restrict__ ssm_p,
                                                 const float* __restrict__ proj,
                                                 const float* __restrict__ A_log,
                                                 const float* __restrict__ Dvec,
                                                 const float* __restrict__ Cin,
                                                 f16* __restrict__ yh)
{
    const int h = blockIdx.x * 256 + threadIdx.x;
    const int c = blockIdx.y;
    const int s0 = c * LCH;

    __shared__ float Bs[LCH][DST];
    __shared__ float Cs[LCH][DST];
    for (int j = threadIdx.x; j < LCH * DST; j += 256) {
        int r = j >> 4, dd = j & 15;
        Bs[r][dd] = ssm_p[(size_t)(s0 + r) * NP + DTR + dd];
        Cs[r][dd] = ssm_p[(size_t)(s0 + r) * NP + DTR + DST + dd];
    }
    __syncthreads();

    float A[DST], st[DST];
    size_t base = ((size_t)c * INTER + h) * DST;
#pragma unroll
    for (int d = 0; d < DST; ++d) {
        A[d] = -__expf(A_log[(size_t)h * DST + d]);
        st[d] = Cin[base + d];
    }
    const float Dv = Dvec[h];

    for (int r = 0; r < LCH; ++r) {
        float dtv = dtb[(size_t)(s0 + r) * INTER + h];
        float hv  = hbuf[(size_t)(s0 + r) * INTER + h];
        float g   = proj[(size_t)(s0 + r) * (2 * INTER) + INTER + h];
        float dh = dtv * hv;
        float y = 0.0f;
#pragma unroll
        for (int d = 0; d < DST; ++d) {
            float da = __expf(dtv * A[d]);
            st[d] = fmaf(da, st[d], dh * Bs[r][d]);
            y = fmaf(st[d], Cs[r][d], y);
        }
        y = fmaf(hv, Dv, y);
        yh[(size_t)(s0 + r) * INTER + h] = (f16)(y * siluf_(g));
    }
}

// ---------------------------------------------------------------------------
extern "C" void kernel_launch(void* const* d_in, const int* in_sizes, int n_in,
                              void* d_out, int out_size, void* d_ws, size_t ws_size,
                              hipStream_t stream)
{
    const float* x      = (const float*)d_in[0];
    const float* W_in   = (const float*)d_in[1];
    const float* conv_w = (const float*)d_in[2];
    const float* conv_b = (const float*)d_in[3];
    const float* W_x    = (const float*)d_in[4];
    const float* W_dt   = (const float*)d_in[5];
    const float* b_dt   = (const float*)d_in[6];
    const float* A_log  = (const float*)d_in[7];
    const float* Dv     = (const float*)d_in[8];
    const float* W_out  = (const float*)d_in[9];
    float* out = (float*)d_out;

    float* ws = (float*)d_ws;
    float* proj  = ws;                          // 8388608
    float* hbuf  = ws + 8388608;                // 4194304
    float* dtb   = ws + 12582912;               // 4194304
    float* ssm_p = ws + 16777216;               // 196608
    float* parts = ws + 16973824;               // 3145728 (KS*SEQ*NP)
    float* Sbuf  = ws + 20119552;               // 2097152
    float* Pbuf  = ws + 22216704;               // 2097152
    float* Cin   = ws + 24313856;               // 2097152
    // aliases (disjoint lifetimes):
    f16* yh      = (f16*)(ws + 16973824);       // on parts[0..2M)   (phase 6-7)
    f16* W_out_t = (f16*)(ws + 19070976);       // on parts[2M..3M)  (phase 5-7)
    f16* xh      = (f16*)(ws + 20119552);       // on Sbuf           (phase 0-1)
    f16* W_in_t  = (f16*)(ws + 21168128);       // on Sbuf/Pbuf      (phase 0-1)
    f16* hh      = (f16*)(ws + 24313856);       // on Cin            (phase 2-3)
    // small tail buffers
    f16* WxT     = (f16*)(ws + 26411008);       // 96*2048 halves
    f16* tsh     = (f16*)(ws + 26509312);       // 2048*64 halves
    f16* WdtT    = (f16*)(ws + 26574848);       // 2048*64 halves

    // 0) conversions for MFMA operands
    cvt_f16<<<(SEQ * HID) / 1024, 256, 0, stream>>>(x, xh);
    transpose_f16<<<dim3(4096 / 32, HID / 32), 256, 0, stream>>>(W_in, W_in_t, HID, 2 * INTER);
    transpose_f16<<<dim3(NP / 32, INTER / 32), 256, 0, stream>>>(W_x, WxT, INTER, NP);
    transpose_f16<<<dim3(INTER / 32, DTR / 32), 256, 0, stream>>>(W_dt, WdtT, DTR, INTER);

    // 1) proj = x @ W_in   (2048 x 4096 x 1024), f16 MFMA
    gemm_f16mfma<128, 128, HID><<<dim3(4096 / 128, SEQ / 128), 256, 0, stream>>>(
        xh, W_in_t, proj, 2 * INTER);

    // 2) h = silu(causal depthwise conv(raw) + b)  -> f32 + f16
    conv_silu<<<(SEQ * INTER / 4) / 256, 256, 0, stream>>>(proj, conv_w, conv_b, hbuf, hh);

    // 3) ssm_p = h @ W_x   (split-K=16 MFMA + reduce; reduce emits ts as f16)
    hwx_mfma<<<dim3(SEQ / 128, KS), 256, 0, stream>>>(hh, WxT, parts);
    reduce_partials<<<(SEQ * NP + 255) / 256, 256, 0, stream>>>(parts, ssm_p, tsh);

    // 4) dt = softplus(ts @ W_dt + b_dt), f16 MFMA with fused epilogue
    dt_mfma<<<dim3(INTER / 128, SEQ / 128), 256, 0, stream>>>(tsh, WdtT, b_dt, dtb);

    // 5) W_out transpose (parts region dead for cols >= 2M floats)
    transpose_f16<<<dim3(HID / 32, INTER / 32), 256, 0, stream>>>(W_out, W_out_t, INTER, HID);

    // 6) chunked SSM scan, fused epilogue -> y in f16 (yh aliases parts)
    ssm_pass1<<<dim3(INTER / 256, NC), 256, 0, stream>>>(dtb, hbuf, ssm_p, A_log, Sbuf, Pbuf);
    ssm_pass2<<<(INTER * DST) / 256, 256, 0, stream>>>(Sbuf, Pbuf, Cin);
    ssm_pass3<<<dim3(INTER / 256, NC), 256, 0, stream>>>(dtb, hbuf, ssm_p, proj, A_log, Dv, Cin, yh);

    // 7) out = y @ W_out   (2048 x 1024 x 2048), f16 MFMA, 64x128 tile
    gemm_f16mfma<64, 128, INTER><<<dim3(HID / 128, SEQ / 64), 256, 0, stream>>>(
        yh, W_out_t, out, HID);
}

// Round 5
// 184.033 us; speedup vs baseline: 6.3801x; 1.0647x over previous
//
#include <hip/hip_runtime.h>
#include <math.h>

#define SEQ   2048
#define HID   1024
#define INTER 2048
#define DST   16
#define DTR   64
#define NP    96   // DTR + 2*DST
#define NC    64   // scan chunks
#define LCH   32   // steps per chunk (NC*LCH == SEQ)
#define KS    16   // split-K factor for h @ W_x

typedef _Float16 f16;
typedef _Float16 f16x8 __attribute__((ext_vector_type(8)));
typedef _Float16 f16x4v __attribute__((ext_vector_type(4)));
typedef float f32x4 __attribute__((ext_vector_type(4)));

__device__ __forceinline__ float sigmoidf_(float x) { return 1.0f / (1.0f + expf(-x)); }
__device__ __forceinline__ float siluf_(float x)    { return x * sigmoidf_(x); }
__device__ __forceinline__ float softplusf_(float x){ return (x > 20.0f) ? x : log1pf(expf(x)); }

// ---------------------------------------------------------------------------
// prep_all: one kernel doing x->f16 + all 4 weight transposes (f32 -> f16^T).
// Block ranges: [0,2048) cvt x | [2048,6144) W_in | [6144,8192) W_out
//               [8192,8384) W_x | [8384,8512) W_dt
// ---------------------------------------------------------------------------
__device__ __forceinline__ void tile_transpose(const float* __restrict__ W,
                                               f16* __restrict__ Wt,
                                               int K, int N, int bx, int by, int tid)
{
    __shared__ float t[32][33];
    const int n0 = bx * 32, k0 = by * 32;
    const int j = tid & 31, i0 = tid >> 5;   // i0: 0..7
#pragma unroll
    for (int r = 0; r < 4; ++r)
        t[i0 + r * 8][j] = W[(size_t)(k0 + i0 + r * 8) * N + n0 + j];
    __syncthreads();
#pragma unroll
    for (int r = 0; r < 4; ++r)
        Wt[(size_t)(n0 + i0 + r * 8) * K + k0 + j] = (f16)t[j][i0 + r * 8];
}

__global__ __launch_bounds__(256) void prep_all(const float* __restrict__ x,
                                                const float* __restrict__ W_in,
                                                const float* __restrict__ W_out,
                                                const float* __restrict__ W_x,
                                                const float* __restrict__ W_dt,
                                                f16* __restrict__ xh,
                                                f16* __restrict__ W_in_t,
                                                f16* __restrict__ W_out_t,
                                                f16* __restrict__ WxT,
                                                f16* __restrict__ WdtT)
{
    const int bid = blockIdx.x, tid = threadIdx.x;
    if (bid < 2048) {
        int i = (bid * 256 + tid) * 4;
        float4 v = *(const float4*)&x[i];
        f16x4v o;
        o.x = (f16)v.x; o.y = (f16)v.y; o.z = (f16)v.z; o.w = (f16)v.w;
        *(f16x4v*)&xh[i] = o;
    } else if (bid < 6144) {
        int t = bid - 2048;                       // W_in: K=1024, N=4096
        tile_transpose(W_in, W_in_t, HID, 4096, t & 127, t >> 7, tid);
    } else if (bid < 8192) {
        int t = bid - 6144;                       // W_out: K=2048, N=1024
        tile_transpose(W_out, W_out_t, INTER, HID, t & 31, t >> 5, tid);
    } else if (bid < 8384) {
        int t = bid - 8192;                       // W_x: K=2048, N=96
        tile_transpose(W_x, WxT, INTER, NP, t % 3, t / 3, tid);
    } else {
        int t = bid - 8384;                       // W_dt: K=64, N=2048
        tile_transpose(W_dt, WdtT, DTR, INTER, t & 63, t >> 6, tid);
    }
}

// ---------------------------------------------------------------------------
// MFMA f16 GEMM: C[M,N] OutT = Ah[M,K] f16 @ Bt[N,K]^T f16.
// m97 structure: BK=64, 4 waves (2x2), global_load_lds width 16, linear LDS.
// ---------------------------------------------------------------------------
template<int BM, int BN, int KK, typename OutT>
__global__ __launch_bounds__(256) void gemm_f16mfma(const f16* __restrict__ Ah,
                                                    const f16* __restrict__ Bt,
                                                    OutT* __restrict__ C,
                                                    int N)
{
    constexpr int BK = 64;
    __shared__ __align__(16) f16 As[BM * BK];
    __shared__ __align__(16) f16 Bs[BN * BK];

    const int tid = threadIdx.x;
    const int wid = tid >> 6, lane = tid & 63;
    const int wr = wid >> 1, wc = wid & 1;
    const int m0 = blockIdx.y * BM, n0 = blockIdx.x * BN;
    const int l15 = lane & 15, lhi = lane >> 4;

    constexpr int MR = BM / 32;
    constexpr int NR = BN / 32;

    f32x4 acc[MR][NR] = {};

    for (int k0 = 0; k0 < KK; k0 += BK) {
        constexpr int CA = BM * BK * 2 / 1024;
#pragma unroll
        for (int c0 = 0; c0 < CA; c0 += 4) {
            int c = c0 + wid;
            int e = c * 64 + lane;
            int row = e >> 3, seg = e & 7;
            __builtin_amdgcn_global_load_lds(
                (const __attribute__((address_space(1))) unsigned int*)
                    (Ah + (size_t)(m0 + row) * KK + k0 + seg * 8),
                (__attribute__((address_space(3))) unsigned int*)(As + c * 512),
                16, 0, 0);
        }
        constexpr int CB = BN * BK * 2 / 1024;
#pragma unroll
        for (int c0 = 0; c0 < CB; c0 += 4) {
            int c = c0 + wid;
            int e = c * 64 + lane;
            int row = e >> 3, seg = e & 7;
            __builtin_amdgcn_global_load_lds(
                (const __attribute__((address_space(1))) unsigned int*)
                    (Bt + (size_t)(n0 + row) * KK + k0 + seg * 8),
                (__attribute__((address_space(3))) unsigned int*)(Bs + c * 512),
                16, 0, 0);
        }
        __syncthreads();

#pragma unroll
        for (int kk = 0; kk < BK; kk += 32) {
            f16x8 af[MR], bf[NR];
#pragma unroll
            for (int i = 0; i < MR; ++i)
                af[i] = *(const f16x8*)&As[(wr * (BM / 2) + i * 16 + l15) * BK + kk + lhi * 8];
#pragma unroll
            for (int n = 0; n < NR; ++n)
                bf[n] = *(const f16x8*)&Bs[(wc * (BN / 2) + n * 16 + l15) * BK + kk + lhi * 8];
#pragma unroll
            for (int i = 0; i < MR; ++i)
#pragma unroll
                for (int n = 0; n < NR; ++n)
                    acc[i][n] = __builtin_amdgcn_mfma_f32_16x16x32_f16(af[i], bf[n], acc[i][n], 0, 0, 0);
        }
        __syncthreads();
    }

    // C/D map: col = lane&15, row = (lane>>4)*4 + reg
#pragma unroll
    for (int i = 0; i < MR; ++i)
#pragma unroll
        for (int n = 0; n < NR; ++n)
#pragma unroll
            for (int r = 0; r < 4; ++r)
                C[(size_t)(m0 + wr * (BM / 2) + i * 16 + lhi * 4 + r) * N
                  + n0 + wc * (BN / 2) + n * 16 + l15] = (OutT)acc[i][n][r];
}

// ---------------------------------------------------------------------------
// h @ W_x split-K MFMA: partials[ks][SEQ][96] = h[:, ks*128:+128] @ WxT^T
// ---------------------------------------------------------------------------
__global__ __launch_bounds__(256) void hwx_mfma(const f16* __restrict__ hh,
                                                const f16* __restrict__ WxT,
                                                float* __restrict__ partials)
{
    constexpr int BM = 128, BN = 96, BK = 64;
    __shared__ __align__(16) f16 As[BM * BK];
    __shared__ __align__(16) f16 Bs[BN * BK];

    const int tid = threadIdx.x;
    const int wid = tid >> 6, lane = tid & 63;
    const int wr = wid >> 1, wc = wid & 1;
    const int m0 = blockIdx.x * BM;
    const int ks = blockIdx.y;
    const int l15 = lane & 15, lhi = lane >> 4;

    constexpr int MR = 4, NR = 3;
    f32x4 acc[MR][NR] = {};

    for (int k0 = ks * 128; k0 < ks * 128 + 128; k0 += BK) {
#pragma unroll
        for (int c0 = 0; c0 < 16; c0 += 4) {
            int c = c0 + wid;
            int e = c * 64 + lane;
            int row = e >> 3, seg = e & 7;
            __builtin_amdgcn_global_load_lds(
                (const __attribute__((address_space(1))) unsigned int*)
                    (hh + (size_t)(m0 + row) * INTER + k0 + seg * 8),
                (__attribute__((address_space(3))) unsigned int*)(As + c * 512),
                16, 0, 0);
        }
#pragma unroll
        for (int c0 = 0; c0 < 12; c0 += 4) {
            int c = c0 + wid;
            int e = c * 64 + lane;
            int row = e >> 3, seg = e & 7;
            __builtin_amdgcn_global_load_lds(
                (const __attribute__((address_space(1))) unsigned int*)
                    (WxT + (size_t)row * INTER + k0 + seg * 8),
                (__attribute__((address_space(3))) unsigned int*)(Bs + c * 512),
                16, 0, 0);
        }
        __syncthreads();

#pragma unroll
        for (int kk = 0; kk < BK; kk += 32) {
            f16x8 af[MR], bf[NR];
#pragma unroll
            for (int i = 0; i < MR; ++i)
                af[i] = *(const f16x8*)&As[(wr * 64 + i * 16 + l15) * BK + kk + lhi * 8];
#pragma unroll
            for (int n = 0; n < NR; ++n)
                bf[n] = *(const f16x8*)&Bs[(wc * 48 + n * 16 + l15) * BK + kk + lhi * 8];
#pragma unroll
            for (int i = 0; i < MR; ++i)
#pragma unroll
                for (int n = 0; n < NR; ++n)
                    acc[i][n] = __builtin_amdgcn_mfma_f32_16x16x32_f16(af[i], bf[n], acc[i][n], 0, 0, 0);
        }
        __syncthreads();
    }

    float* P = partials + (size_t)ks * (SEQ * NP);
#pragma unroll
    for (int i = 0; i < MR; ++i)
#pragma unroll
        for (int n = 0; n < NR; ++n)
#pragma unroll
            for (int r = 0; r < 4; ++r)
                P[(size_t)(m0 + wr * 64 + i * 16 + lhi * 4 + r) * NP
                  + wc * 48 + n * 16 + l15] = acc[i][n][r];
}

__global__ __launch_bounds__(256) void reduce_partials(const float* __restrict__ partials,
                                                       float* __restrict__ ssm_p,
                                                       f16* __restrict__ tsh)
{
    int i = blockIdx.x * 256 + threadIdx.x;
    if (i < SEQ * NP) {
        float a = 0.0f;
#pragma unroll
        for (int c = 0; c < KS; ++c) a += partials[(size_t)c * (SEQ * NP) + i];
        int j = i % NP;
        if (j < DTR) tsh[(size_t)(i / NP) * DTR + j] = (f16)a;
        else         ssm_p[i] = a;
    }
}

// ---------------------------------------------------------------------------
// dt = softplus(ts @ W_dt + b_dt), f16 MFMA, K=64 single staging iteration.
// ---------------------------------------------------------------------------
__global__ __launch_bounds__(256) void dt_mfma(const f16* __restrict__ tsh,
                                               const f16* __restrict__ WdtT,
                                               const float* __restrict__ bdt,
                                               f16* __restrict__ dtbh)
{
    constexpr int BM = 128, BN = 128, BK = 64;
    __shared__ __align__(16) f16 As[BM * BK];
    __shared__ __align__(16) f16 Bs[BN * BK];

    const int tid = threadIdx.x;
    const int wid = tid >> 6, lane = tid & 63;
    const int wr = wid >> 1, wc = wid & 1;
    const int m0 = blockIdx.y * BM, n0 = blockIdx.x * BN;
    const int l15 = lane & 15, lhi = lane >> 4;

    constexpr int MR = 4, NR = 4;
    f32x4 acc[MR][NR] = {};

#pragma unroll
    for (int c0 = 0; c0 < 16; c0 += 4) {
        int c = c0 + wid;
        int e = c * 64 + lane;
        int row = e >> 3, seg = e & 7;
        __builtin_amdgcn_global_load_lds(
            (const __attribute__((address_space(1))) unsigned int*)
                (tsh + (size_t)(m0 + row) * DTR + seg * 8),
            (__attribute__((address_space(3))) unsigned int*)(As + c * 512),
            16, 0, 0);
        __builtin_amdgcn_global_load_lds(
            (const __attribute__((address_space(1))) unsigned int*)
                (WdtT + (size_t)(n0 + row) * DTR + seg * 8),
            (__attribute__((address_space(3))) unsigned int*)(Bs + c * 512),
            16, 0, 0);
    }
    __syncthreads();

#pragma unroll
    for (int kk = 0; kk < 64; kk += 32) {
        f16x8 af[MR], bf[NR];
#pragma unroll
        for (int i = 0; i < MR; ++i)
            af[i] = *(const f16x8*)&As[(wr * 64 + i * 16 + l15) * BK + kk + lhi * 8];
#pragma unroll
        for (int n = 0; n < NR; ++n)
            bf[n] = *(const f16x8*)&Bs[(wc * 64 + n * 16 + l15) * BK + kk + lhi * 8];
#pragma unroll
        for (int i = 0; i < MR; ++i)
#pragma unroll
            for (int n = 0; n < NR; ++n)
                acc[i][n] = __builtin_amdgcn_mfma_f32_16x16x32_f16(af[i], bf[n], acc[i][n], 0, 0, 0);
    }

#pragma unroll
    for (int i = 0; i < MR; ++i)
#pragma unroll
        for (int n = 0; n < NR; ++n) {
            int col = n0 + wc * 64 + n * 16 + l15;
            float bv = bdt[col];
#pragma unroll
            for (int r = 0; r < 4; ++r)
                dtbh[(size_t)(m0 + wr * 64 + i * 16 + lhi * 4 + r) * INTER + col] =
                    (f16)softplusf_(acc[i][n][r] + bv);
        }
}

// ---------------------------------------------------------------------------
// Depthwise causal conv (K=4) + bias + SiLU; f16 in (proj raw half), f16 out.
// ---------------------------------------------------------------------------
__global__ __launch_bounds__(256) void conv_silu(const f16* __restrict__ projh,
                                                 const float* __restrict__ cw,
                                                 const float* __restrict__ cb,
                                                 f16* __restrict__ hh)
{
    int idx = blockIdx.x * 256 + threadIdx.x;   // over SEQ*INTER/8
    int c8 = (idx & (INTER / 8 - 1)) * 8;
    int s = idx >> 8;
    float acc[8];
#pragma unroll
    for (int j = 0; j < 8; ++j) acc[j] = cb[c8 + j];
#pragma unroll
    for (int k = 0; k < 4; ++k) {
        int sp = s + k - 3;
        if (sp >= 0) {
            f16x8 p = *(const f16x8*)&projh[(size_t)sp * (2 * INTER) + c8];
#pragma unroll
            for (int j = 0; j < 8; ++j)
                acc[j] = fmaf((float)p[j], cw[k * INTER + c8 + j], acc[j]);
        }
    }
    f16x8 o;
#pragma unroll
    for (int j = 0; j < 8; ++j) o[j] = (f16)siluf_(acc[j]);
    *(f16x8*)&hh[(size_t)idx * 8] = o;
}

// ---------------------------------------------------------------------------
// Chunked parallel scan (pass1/2/3); f16 dt/h/gate inputs, f16 y output.
// ---------------------------------------------------------------------------
__global__ __launch_bounds__(256) void ssm_pass1(const f16* __restrict__ dtbh,
                                                 const f16* __restrict__ hh,
                                                 const float* __restrict__ ssm_p,
                                                 const float* __restrict__ A_log,
                                                 float* __restrict__ Sbuf,
                                                 float* __restrict__ Pbuf)
{
    const int h = blockIdx.x * 256 + threadIdx.x;
    const int c = blockIdx.y;
    const int s0 = c * LCH;

    __shared__ float Bs[LCH][DST];
    for (int j = threadIdx.x; j < LCH * DST; j += 256) {
        int r = j >> 4, dd = j & 15;
        Bs[r][dd] = ssm_p[(size_t)(s0 + r) * NP + DTR + dd];
    }
    __syncthreads();

    float A[DST], st[DST], P[DST];
#pragma unroll
    for (int d = 0; d < DST; ++d) {
        A[d] = -__expf(A_log[(size_t)h * DST + d]);
        st[d] = 0.0f;
        P[d] = 1.0f;
    }

    for (int r = 0; r < LCH; ++r) {
        float dtv = (float)dtbh[(size_t)(s0 + r) * INTER + h];
        float hv  = (float)hh[(size_t)(s0 + r) * INTER + h];
        float dh = dtv * hv;
#pragma unroll
        for (int d = 0; d < DST; ++d) {
            float da = __expf(dtv * A[d]);
            st[d] = fmaf(da, st[d], dh * Bs[r][d]);
            P[d] *= da;
        }
    }

    size_t base = ((size_t)c * INTER + h) * DST;
#pragma unroll
    for (int d = 0; d < DST; d += 4) {
        *(float4*)&Sbuf[base + d] = make_float4(st[d], st[d+1], st[d+2], st[d+3]);
        *(float4*)&Pbuf[base + d] = make_float4(P[d], P[d+1], P[d+2], P[d+3]);
    }
}

__global__ __launch_bounds__(256) void ssm_pass2(const float* __restrict__ Sbuf,
                                                 const float* __restrict__ Pbuf,
                                                 float* __restrict__ Cin)
{
    int i = blockIdx.x * 256 + threadIdx.x;     // over INTER*DST = 32768
    float carry = 0.0f;
    for (int c = 0; c < NC; ++c) {
        size_t idx = (size_t)c * (INTER * DST) + i;
        Cin[idx] = carry;
        carry = fmaf(Pbuf[idx], carry, Sbuf[idx]);
    }
}

__global__ __launch_bounds__(256) void ssm_pass3(const f16* __restrict__ dtbh,
                                                 const f16* __restrict__ hh,
                                                 const float* __restrict__ ssm_p,
                                                 const f16* __restrict__ projh,
                                                 const float* __restrict__ A_log,
                                                 const float* __restrict__ Dvec,
                                                 const float* __restrict__ Cin,
                                                 f16* __restrict__ yh)
{
    const int h = blockIdx.x * 256 + threadIdx.x;
    const int c = blockIdx.y;
    const int s0 = c * LCH;

    __shared__ float Bs[LCH][DST];
    __shared__ float Cs[LCH][DST];
    for (int j = threadIdx.x; j < LCH * DST; j += 256) {
        int r = j >> 4, dd = j & 15;
        Bs[r][dd] = ssm_p[(size_t)(s0 + r) * NP + DTR + dd];
        Cs[r][dd] = ssm_p[(size_t)(s0 + r) * NP + DTR + DST + dd];
    }
    __syncthreads();

    float A[DST], st[DST];
    size_t base = ((size_t)c * INTER + h) * DST;
#pragma unroll
    for (int d = 0; d < DST; ++d) {
        A[d] = -__expf(A_log[(size_t)h * DST + d]);
        st[d] = Cin[base + d];
    }
    const float Dv = Dvec[h];

    for (int r = 0; r < LCH; ++r) {
        float dtv = (float)dtbh[(size_t)(s0 + r) * INTER + h];
        float hv  = (float)hh[(size_t)(s0 + r) * INTER + h];
        float g   = (float)projh[(size_t)(s0 + r) * (2 * INTER) + INTER + h];
        float dh = dtv * hv;
        float y = 0.0f;
#pragma unroll
        for (int d = 0; d < DST; ++d) {
            float da = __expf(dtv * A[d]);
            st[d] = fmaf(da, st[d], dh * Bs[r][d]);
            y = fmaf(st[d], Cs[r][d], y);
        }
        y = fmaf(hv, Dv, y);
        yh[(size_t)(s0 + r) * INTER + h] = (f16)(y * siluf_(g));
    }
}

// ---------------------------------------------------------------------------
extern "C" void kernel_launch(void* const* d_in, const int* in_sizes, int n_in,
                              void* d_out, int out_size, void* d_ws, size_t ws_size,
                              hipStream_t stream)
{
    const float* x      = (const float*)d_in[0];
    const float* W_in   = (const float*)d_in[1];
    const float* conv_w = (const float*)d_in[2];
    const float* conv_b = (const float*)d_in[3];
    const float* W_x    = (const float*)d_in[4];
    const float* W_dt   = (const float*)d_in[5];
    const float* b_dt   = (const float*)d_in[6];
    const float* A_log  = (const float*)d_in[7];
    const float* Dv     = (const float*)d_in[8];
    const float* W_out  = (const float*)d_in[9];
    float* out = (float*)d_out;

    float* ws = (float*)d_ws;
    // flat layout, no aliasing (~98 MB total; float-element offsets)
    f16*  projh  = (f16*)ws;                     // 8,388,608 halves
    f16*  hh     = (f16*)(ws + 4194304);         // 4,194,304 halves
    f16*  dtbh   = (f16*)(ws + 6291456);         // 4,194,304 halves
    f16*  yh     = (f16*)(ws + 8388608);         // 4,194,304 halves
    f16*  xh     = (f16*)(ws + 10485760);        // 2,097,152 halves
    f16*  W_in_t = (f16*)(ws + 11534336);        // 4,194,304 halves
    f16*  W_out_t= (f16*)(ws + 13631488);        // 2,097,152 halves
    f16*  WxT    = (f16*)(ws + 14680064);        // 196,608 halves
    f16*  tsh    = (f16*)(ws + 14778368);        // 131,072 halves
    f16*  WdtT   = (f16*)(ws + 14843904);        // 131,072 halves
    float* ssm_p = ws + 14909440;                // 196,608 floats
    float* parts = ws + 15106048;                // 3,145,728 floats
    float* Sbuf  = ws + 18251776;                // 2,097,152 floats
    float* Pbuf  = ws + 20348928;                // 2,097,152 floats
    float* Cin   = ws + 22446080;                // 2,097,152 floats

    // 0) all conversions/transposes in one kernel
    prep_all<<<8512, 256, 0, stream>>>(x, W_in, W_out, W_x, W_dt,
                                       xh, W_in_t, W_out_t, WxT, WdtT);

    // 1) proj = x @ W_in (2048 x 4096 x 1024), f16 MFMA -> f16 output
    gemm_f16mfma<128, 128, HID, f16><<<dim3(4096 / 128, SEQ / 128), 256, 0, stream>>>(
        xh, W_in_t, projh, 2 * INTER);

    // 2) h = silu(conv(raw) + b) -> f16
    conv_silu<<<(SEQ * INTER / 8) / 256, 256, 0, stream>>>(projh, conv_w, conv_b, hh);

    // 3) ssm_p = h @ W_x (split-K=16 MFMA + reduce; ts goes straight to f16)
    hwx_mfma<<<dim3(SEQ / 128, KS), 256, 0, stream>>>(hh, WxT, parts);
    reduce_partials<<<(SEQ * NP + 255) / 256, 256, 0, stream>>>(parts, ssm_p, tsh);

    // 4) dt = softplus(ts @ W_dt + b_dt) -> f16
    dt_mfma<<<dim3(INTER / 128, SEQ / 128), 256, 0, stream>>>(tsh, WdtT, b_dt, dtbh);

    // 5) chunked SSM scan, fused epilogue -> y f16
    ssm_pass1<<<dim3(INTER / 256, NC), 256, 0, stream>>>(dtbh, hh, ssm_p, A_log, Sbuf, Pbuf);
    ssm_pass2<<<(INTER * DST) / 256, 256, 0, stream>>>(Sbuf, Pbuf, Cin);
    ssm_pass3<<<dim3(INTER / 256, NC), 256, 0, stream>>>(dtbh, hh, ssm_p, projh, A_log, Dv, Cin, yh);

    // 6) out = y @ W_out (2048 x 1024 x 2048), f16 MFMA -> f32 output
    gemm_f16mfma<64, 128, INTER, float><<<dim3(HID / 128, SEQ / 64), 256, 0, stream>>>(
        yh, W_out_t, out, HID);
}